// Round 1
// 145.577 us; speedup vs baseline: 1.0240x; 1.0240x over previous
//
#include <hip/hip_runtime.h>
#include <cmath>

// Problem constants: B=32768, N=17, D=2, K=3, H=64
#define NBATCH 32768
#define NJOINT 17
#define OUT0_ELEMS (NBATCH * NJOINT * 15)          // out[B,N,3,5]
#define KJS_OFF    OUT0_ELEMS                      // k_js[B,N]
#define MASK_OFF   (KJS_OFF + NBATCH * NJOINT)     // mask[B,N,3]

// fp64 weight workspace layout (per joint n, stride 774 doubles):
//  [0,128)   kW1  ([2][64]: row0=+0, row1=+64)
//  [128,192) kb1
//  [192,384) kW2  ([64][3])
//  [384,387) kb2
//  +387      same for the w-MLP
#define WN_STRIDE 774
#define WS_DOUBLES (NJOINT * WN_STRIDE)

__device__ __forceinline__ float sel3f(int i, float a, float b, float c) {
    return (i == 0) ? a : ((i == 1) ? b : c);
}

// --------------------------------------------------------------------------
// Prelude: convert k/w weights to fp64 once per launch (removes ~768
// v_cvt_f64_f32 per point from the hot loops).
// --------------------------------------------------------------------------
__global__ void cvt_weights_f64(
    const float* __restrict__ kW1, const float* __restrict__ kb1,
    const float* __restrict__ kW2, const float* __restrict__ kb2,
    const float* __restrict__ wW1, const float* __restrict__ wb1,
    const float* __restrict__ wW2, const float* __restrict__ wb2,
    double* __restrict__ dws)
{
    const int n = blockIdx.x;
    double* o = dws + (size_t)n * WN_STRIDE;
    for (int i = threadIdx.x; i < WN_STRIDE; i += blockDim.x) {
        int j = i;
        const float* W1 = kW1; const float* b1 = kb1;
        const float* W2 = kW2; const float* b2 = kb2;
        if (j >= 387) { j -= 387; W1 = wW1; b1 = wb1; W2 = wW2; b2 = wb2; }
        float v;
        if (j < 128)      v = W1[n * 128 + j];
        else if (j < 192) v = b1[n * 64 + (j - 128)];
        else if (j < 384) v = W2[n * 192 + (j - 192)];
        else              v = b2[n * 3 + (j - 384)];
        o[i] = (double)v;
    }
}

// --------------------------------------------------------------------------
// Per-point compute: bit-identical math to the previous passing kernel.
// k/w logits in fp64 (discrete argmax/argsort decisions), bMLP in fp32.
// --------------------------------------------------------------------------
template<bool USE_WS>
__device__ __forceinline__ void compute_point(
    int n, float x0f, float x1f,
    const float* __restrict__ kW1, const float* __restrict__ kb1,
    const float* __restrict__ kW2, const float* __restrict__ kb2,
    const float* __restrict__ wW1, const float* __restrict__ wb1,
    const float* __restrict__ wW2, const float* __restrict__ wb2,
    const float* __restrict__ bW1, const float* __restrict__ bb1,
    const float* __restrict__ bW2, const float* __restrict__ bb2,
    const double* __restrict__ dws,
    float r[15], int& kj_out)
{
    const double x0 = (double)x0f, x1 = (double)x1f;
    double kl0, kl1, kl2, wl0, wl1, wl2;

    if constexpr (USE_WS) {
        const double* Wn = dws + (size_t)n * WN_STRIDE;
        {   // kMLP (fp64, pre-converted weights -> scalar double loads, no cvt)
            const double* W1a = Wn;
            const double* W1b = Wn + 64;
            const double* b1  = Wn + 128;
            const double* W2  = Wn + 192;
            kl0 = Wn[384]; kl1 = Wn[385]; kl2 = Wn[386];
            #pragma unroll 4
            for (int h = 0; h < 64; ++h) {
                double hv = fmax(fma(x1, W1b[h], fma(x0, W1a[h], b1[h])), 0.0);
                kl0 = fma(hv, W2[h * 3 + 0], kl0);
                kl1 = fma(hv, W2[h * 3 + 1], kl1);
                kl2 = fma(hv, W2[h * 3 + 2], kl2);
            }
        }
        {   // wMLP (fp64)
            const double* W1a = Wn + 387;
            const double* W1b = Wn + 451;
            const double* b1  = Wn + 515;
            const double* W2  = Wn + 579;
            wl0 = Wn[771]; wl1 = Wn[772]; wl2 = Wn[773];
            #pragma unroll 4
            for (int h = 0; h < 64; ++h) {
                double hv = fmax(fma(x1, W1b[h], fma(x0, W1a[h], b1[h])), 0.0);
                wl0 = fma(hv, W2[h * 3 + 0], wl0);
                wl1 = fma(hv, W2[h * 3 + 1], wl1);
                wl2 = fma(hv, W2[h * 3 + 2], wl2);
            }
        }
    } else {
        {   // kMLP fallback: cvt in loop (identical to previous kernel)
            const float* W1a = kW1 + n * 128;
            const float* W1b = W1a + 64;
            const float* b1  = kb1 + n * 64;
            const float* W2  = kW2 + n * 192;
            kl0 = (double)kb2[n * 3 + 0];
            kl1 = (double)kb2[n * 3 + 1];
            kl2 = (double)kb2[n * 3 + 2];
            #pragma unroll 4
            for (int h = 0; h < 64; ++h) {
                double hv = fma(x1, (double)W1b[h], fma(x0, (double)W1a[h], (double)b1[h]));
                hv = fmax(hv, 0.0);
                kl0 = fma(hv, (double)W2[h * 3 + 0], kl0);
                kl1 = fma(hv, (double)W2[h * 3 + 1], kl1);
                kl2 = fma(hv, (double)W2[h * 3 + 2], kl2);
            }
        }
        {   // wMLP fallback
            const float* W1a = wW1 + n * 128;
            const float* W1b = W1a + 64;
            const float* b1  = wb1 + n * 64;
            const float* W2  = wW2 + n * 192;
            wl0 = (double)wb2[n * 3 + 0];
            wl1 = (double)wb2[n * 3 + 1];
            wl2 = (double)wb2[n * 3 + 2];
            #pragma unroll 4
            for (int h = 0; h < 64; ++h) {
                double hv = fma(x1, (double)W1b[h], fma(x0, (double)W1a[h], (double)b1[h]));
                hv = fmax(hv, 0.0);
                wl0 = fma(hv, (double)W2[h * 3 + 0], wl0);
                wl1 = fma(hv, (double)W2[h * 3 + 1], wl1);
                wl2 = fma(hv, (double)W2[h * 3 + 2], wl2);
            }
        }
    }

    // argmax (first-occurrence, jnp.argmax semantics)
    int kj = 0;
    {
        double m = kl0;
        if (kl1 > m) { m = kl1; kj = 1; }
        if (kl2 > m) { kj = 2; }
    }
    kj_out = kj;

    // stable descending argsort of 3 (jnp.argsort(-w))
    int i0 = 0;
    {
        double m = wl0;
        if (wl1 > m) { m = wl1; i0 = 1; }
        if (wl2 > m) { i0 = 2; }
    }
    const int ia = (i0 == 0) ? 1 : 0;
    const int ib = (i0 == 2) ? 1 : 2;
    const double wa = ia ? wl1 : wl0;
    const double wb = (ib == 1) ? wl1 : wl2;
    const int i1 = (wb > wa) ? ib : ia;
    const int i2 = (wb > wa) ? ia : ib;

    // softmax weights (original order into out[...,0])
    const double mw = fmax(fmax(wl0, wl1), wl2);
    const float e0 = __expf((float)(wl0 - mw));
    const float e1 = __expf((float)(wl1 - mw));
    const float e2 = __expf((float)(wl2 - mw));
    const float inv = 1.0f / (e0 + e1 + e2);
    const float p0 = e0 * inv, p1 = e1 * inv, p2 = e2 * inv;

    // bMLP (fp32): 2 -> 128 -> 12
    float acc[12];
    {
        const float* W1a = bW1 + n * 256;
        const float* W1b = W1a + 128;
        const float* b1  = bb1 + n * 128;
        const float* W2  = bW2 + n * 1536;
        const float* b2  = bb2 + n * 12;
        #pragma unroll
        for (int j = 0; j < 12; ++j) acc[j] = b2[j];
        #pragma unroll 4
        for (int h = 0; h < 128; ++h) {
            float hv = fmaxf(fmaf(x1f, W1b[h], fmaf(x0f, W1a[h], b1[h])), 0.0f);
            #pragma unroll
            for (int j = 0; j < 12; ++j)
                acc[j] = fmaf(hv, W2[h * 12 + j], acc[j]);
        }
    }

    // epilogue: gather by sort order
    r[0]  = p0; r[5] = p1; r[10] = p2;
    r[1]  = sel3f(i0, acc[0], acc[4], acc[8]);
    r[2]  = sel3f(i0, acc[1], acc[5], acc[9]);
    r[3]  = __expf(sel3f(i0, acc[2], acc[6], acc[10]));
    r[4]  = __expf(sel3f(i0, acc[3], acc[7], acc[11]));
    r[6]  = sel3f(i1, acc[0], acc[4], acc[8]);
    r[7]  = sel3f(i1, acc[1], acc[5], acc[9]);
    r[8]  = __expf(sel3f(i1, acc[2], acc[6], acc[10]));
    r[9]  = __expf(sel3f(i1, acc[3], acc[7], acc[11]));
    r[11] = sel3f(i2, acc[0], acc[4], acc[8]);
    r[12] = sel3f(i2, acc[1], acc[5], acc[9]);
    r[13] = __expf(sel3f(i2, acc[2], acc[6], acc[10]));
    r[14] = __expf(sel3f(i2, acc[3], acc[7], acc[11]));
}

// --------------------------------------------------------------------------
// Main kernel. Block = 4 waves; wave w handles n = 4*blockIdx.y + w
// (readfirstlane -> wave-uniform -> weights stay s_load); lane handles
// b = blockIdx.x*64 + lane. Output tile (64 b x 4 consecutive n) staged in
// LDS (stride-17 slots: 17 coprime to 32 banks -> 2-way write aliasing),
// then written back as contiguous 240B-per-b runs: coalesced stores, and
// adjacent-n chunks of a row come from the SAME block -> L2 full-line merge.
// --------------------------------------------------------------------------
template<bool USE_WS>
__global__ __launch_bounds__(256) void mdn_fused(
    const float* __restrict__ pred_pts,
    const float* __restrict__ kW1, const float* __restrict__ kb1,
    const float* __restrict__ kW2, const float* __restrict__ kb2,
    const float* __restrict__ wW1, const float* __restrict__ wb1,
    const float* __restrict__ wW2, const float* __restrict__ wb2,
    const float* __restrict__ bW1, const float* __restrict__ bb1,
    const float* __restrict__ bW2, const float* __restrict__ bb2,
    float* __restrict__ out,
    const double* __restrict__ dws)
{
    const int l    = threadIdx.x;
    const int w    = l >> 6;           // wave id 0..3
    const int lane = l & 63;
    const int bx   = blockIdx.x;
    const int by   = blockIdx.y;       // 0..4
    const int n0   = by * 4;

    int n = n0 + w;
    if (n >= NJOINT) return;           // only by==4 waves 1..3; no barriers on this path
    n = __builtin_amdgcn_readfirstlane(n);

    const int b = bx * 64 + lane;
    const int p = b * NJOINT + n;

    const float2 xv = *reinterpret_cast<const float2*>(pred_pts + 2 * p);

    float r[15];
    int kj;
    compute_point<USE_WS>(n, xv.x, xv.y,
                          kW1, kb1, kW2, kb2, wW1, wb1, wW2, wb2,
                          bW1, bb1, bW2, bb2, dws, r, kj);

    if (by == 4) {
        // n==16 remainder: 1/17 of traffic, direct stores (wave 0 only).
        float* o = out + (size_t)p * 15;
        #pragma unroll
        for (int i = 0; i < 15; ++i) o[i] = r[i];
        out[KJS_OFF + p] = (float)(kj + 1);
        float* mk = out + MASK_OFF + (size_t)p * 3;
        mk[0] = 1.0f;
        mk[1] = (kj >= 1) ? 1.0f : 0.0f;
        mk[2] = (kj >= 2) ? 1.0f : 0.0f;
        return;
    }

    // ---- stage tile in LDS: slot = w*64+lane, stride 17 dwords ----
    __shared__ float s_out[256 * 17];          // 17408 B -> 8 blocks/CU
    {
        float* so = s_out + (w * 64 + lane) * 17;
        #pragma unroll
        for (int j = 0; j < 15; ++j) so[j] = r[j];
        so[15] = (float)(kj + 1);
    }
    __syncthreads();

    // ---- coalesced write-back: 16 rounds, lanes 0..239 ----
    // round rr writes chunks c = 4*rr + c_off; chunk c = 60 contiguous dwords
    // of out for (b = bx*64+c, n = n0..n0+3).
    if (l < 240) {
        const int c_off = l / 60;              // 0..3
        const int jj    = l - c_off * 60;      // 0..59
        const int nl    = jj / 15;             // 0..3
        const int j     = jj - nl * 15;        // 0..14
        const int lbase = nl * 1088 + c_off * 17 + j;   // (nl*64+c_off)*17 + j
        size_t g = (size_t)((bx * 64 + c_off) * NJOINT + n0) * 15 + jj;
        #pragma unroll
        for (int rr = 0; rr < 16; ++rr) {
            out[g] = s_out[lbase + 68 * rr];   // +68 dwords per +4 chunks
            g += 1020;                          // 4 * 17 * 15 dwords
        }
    }

    // ---- k_js + mask, derived from staged kj, per-b contiguous groups ----
    {
        const int bl  = l >> 2;                // 0..63
        const int nlr = l & 3;                 // 0..3
        const float kjf = s_out[(nlr * 64 + bl) * 17 + 15];
        const int pg = (bx * 64 + bl) * NJOINT + n0 + nlr;
        out[KJS_OFF + pg] = kjf;
        float* mk = out + MASK_OFF + (size_t)pg * 3;
        mk[0] = 1.0f;
        mk[1] = (kjf >= 1.5f) ? 1.0f : 0.0f;
        mk[2] = (kjf >= 2.5f) ? 1.0f : 0.0f;
    }
}

extern "C" void kernel_launch(void* const* d_in, const int* in_sizes, int n_in,
                              void* d_out, int out_size, void* d_ws, size_t ws_size,
                              hipStream_t stream) {
    (void)in_sizes; (void)n_in; (void)out_size;
    const bool use_ws = (d_ws != nullptr) && (ws_size >= (size_t)WS_DOUBLES * sizeof(double));
    dim3 grid(NBATCH / 64, 5);
    if (use_ws) {
        cvt_weights_f64<<<NJOINT, 256, 0, stream>>>(
            (const float*)d_in[1], (const float*)d_in[2],
            (const float*)d_in[3], (const float*)d_in[4],
            (const float*)d_in[5], (const float*)d_in[6],
            (const float*)d_in[7], (const float*)d_in[8],
            (double*)d_ws);
        mdn_fused<true><<<grid, 256, 0, stream>>>(
            (const float*)d_in[0],
            (const float*)d_in[1], (const float*)d_in[2],
            (const float*)d_in[3], (const float*)d_in[4],
            (const float*)d_in[5], (const float*)d_in[6],
            (const float*)d_in[7], (const float*)d_in[8],
            (const float*)d_in[9], (const float*)d_in[10],
            (const float*)d_in[11], (const float*)d_in[12],
            (float*)d_out, (const double*)d_ws);
    } else {
        mdn_fused<false><<<grid, 256, 0, stream>>>(
            (const float*)d_in[0],
            (const float*)d_in[1], (const float*)d_in[2],
            (const float*)d_in[3], (const float*)d_in[4],
            (const float*)d_in[5], (const float*)d_in[6],
            (const float*)d_in[7], (const float*)d_in[8],
            (const float*)d_in[9], (const float*)d_in[10],
            (const float*)d_in[11], (const float*)d_in[12],
            (float*)d_out, nullptr);
    }
}